// Round 9
// baseline (1319.654 us; speedup 1.0000x reference)
//
#include <hip/hip_runtime.h>
#include <cstdint>

// ============================================================================
// ScaledCorticalColumn — R9: fix rule-#20 scratch allocation in attn.
// R7/R8's key[4][32] was runtime-indexed (chunk loop var) -> compiler put it
// in LOCAL MEMORY (VGPR_Count=116 despite ~200 live values; radix loop then
// re-read all keys from scratch per bit). Fix: #pragma unroll the chunk loop
// so every key index is compile-time -> keys stay in VGPRs.
// Everything else byte-identical to R8 (clean A/B).
// ============================================================================

#define DEV __device__ __forceinline__

constexpr int B_  = 2;
constexpr int N_  = 2048;
constexpr int D_  = 1024;
constexpr int H_  = 16;
constexpr int HD_ = 64;
constexpr int M_  = B_ * N_;          // 4096 rows
constexpr float EPS_ = 1e-5f;

using short8 = __attribute__((ext_vector_type(8))) short;
using f32x4  = __attribute__((ext_vector_type(4))) float;

DEV float4 ld4(const float* p) { return *reinterpret_cast<const float4*>(p); }
DEV void   st4(float* p, float4 v) { *reinterpret_cast<float4*>(p) = v; }

// bf16 round-to-nearest-even split helpers
DEV unsigned short bf16r(float x) {
  unsigned u = __float_as_uint(x);
  u += 0x7fffu + ((u >> 16) & 1u);
  return (unsigned short)(u >> 16);
}
DEV float bf2f(unsigned short h) { return __uint_as_float(((unsigned)h) << 16); }

// order-preserving float<->uint key map (monotone bijection, tie-exact)
DEV unsigned fkey(float f) {
  unsigned u = __float_as_uint(f);
  return u ^ ((unsigned)((int)u >> 31) | 0x80000000u);
}
DEV float fval(unsigned k) {
  unsigned u = (k & 0x80000000u) ? (k ^ 0x80000000u) : ~k;
  return __uint_as_float(u);
}

// ---------------------------------------------------------------------------
// Weight transpose-convert: W f32 [K][N] -> Thi/Tlo bf16 [N][K]. 32x32 tiles.
// ---------------------------------------------------------------------------
__global__ __launch_bounds__(256) void wconv_kernel(const float* __restrict__ W,
                                                    unsigned short* __restrict__ Thi,
                                                    unsigned short* __restrict__ Tlo,
                                                    int K, int N) {
  __shared__ float t[32][33];
  const int k0 = blockIdx.y * 32, n0 = blockIdx.x * 32;
  const int tid = threadIdx.x;
  const int r = tid >> 3, c4 = (tid & 7) * 4;
  float4 v = ld4(W + (size_t)(k0 + r) * N + n0 + c4);
  t[r][c4 + 0] = v.x; t[r][c4 + 1] = v.y; t[r][c4 + 2] = v.z; t[r][c4 + 3] = v.w;
  __syncthreads();
  const int n = tid >> 3, kc = (tid & 7) * 4;
  ushort4 hv, lv;
  {
    float x0 = t[kc + 0][n], x1 = t[kc + 1][n], x2 = t[kc + 2][n], x3 = t[kc + 3][n];
    hv.x = bf16r(x0); lv.x = bf16r(x0 - bf2f(hv.x));
    hv.y = bf16r(x1); lv.y = bf16r(x1 - bf2f(hv.y));
    hv.z = bf16r(x2); lv.z = bf16r(x2 - bf2f(hv.z));
    hv.w = bf16r(x3); lv.w = bf16r(x3 - bf2f(hv.w));
  }
  *reinterpret_cast<ushort4*>(&Thi[(size_t)(n0 + n) * K + k0 + kc]) = hv;
  *reinterpret_cast<ushort4*>(&Tlo[(size_t)(n0 + n) * K + k0 + kc]) = lv;
}

// ---------------------------------------------------------------------------
// LayerNorm: one block per row; writes bf16 hi/lo pair planes.
// ---------------------------------------------------------------------------
__global__ __launch_bounds__(256) void ln_kernel(const float* __restrict__ in,
                                                 const float* __restrict__ g,
                                                 const float* __restrict__ b,
                                                 unsigned short* __restrict__ ohi,
                                                 unsigned short* __restrict__ olo) {
  const int row = blockIdx.x;
  const int t = threadIdx.x;
  float4 v = ld4(in + (size_t)row * D_ + t * 4);
  float s  = v.x + v.y + v.z + v.w;
  float ss = v.x * v.x + v.y * v.y + v.z * v.z + v.w * v.w;
  #pragma unroll
  for (int o = 32; o; o >>= 1) { s += __shfl_down(s, o); ss += __shfl_down(ss, o); }
  __shared__ float rs[4], rss[4];
  const int wid = t >> 6, lane = t & 63;
  if (lane == 0) { rs[wid] = s; rss[wid] = ss; }
  __syncthreads();
  s  = rs[0] + rs[1] + rs[2] + rs[3];
  ss = rss[0] + rss[1] + rss[2] + rss[3];
  const float mean = s * (1.f / D_);
  const float var  = ss * (1.f / D_) - mean * mean;
  const float rstd = rsqrtf(var + EPS_);
  float4 gv = ld4(g + t * 4);
  float4 bv = ld4(b + t * 4);
  float o0 = (v.x - mean) * rstd * gv.x + bv.x;
  float o1 = (v.y - mean) * rstd * gv.y + bv.y;
  float o2 = (v.z - mean) * rstd * gv.z + bv.z;
  float o3 = (v.w - mean) * rstd * gv.w + bv.w;
  ushort4 hv, lv;
  hv.x = bf16r(o0); lv.x = bf16r(o0 - bf2f(hv.x));
  hv.y = bf16r(o1); lv.y = bf16r(o1 - bf2f(hv.y));
  hv.z = bf16r(o2); lv.z = bf16r(o2 - bf2f(hv.z));
  hv.w = bf16r(o3); lv.w = bf16r(o3 - bf2f(hv.w));
  *reinterpret_cast<ushort4*>(&ohi[(size_t)row * D_ + t * 4]) = hv;
  *reinterpret_cast<ushort4*>(&olo[(size_t)row * D_ + t * 4]) = lv;
}

// ---------------------------------------------------------------------------
// Split-bf16 GEMM (unchanged)
// ---------------------------------------------------------------------------
enum { GO_PAIR_BIAS = 0, GO_F32 = 1, GO_F32_BIAS_RESPAIR = 2,
       GO_F32_BIAS_RESF32 = 3, GO_F32_RES_NB = 4, GO_PAIR_NB = 5 };

template <int EPI>
__global__ __launch_bounds__(256) void gemm_sb(const unsigned short* __restrict__ Ah,
                                               const unsigned short* __restrict__ Al,
                                               const unsigned short* __restrict__ Bh,
                                               const unsigned short* __restrict__ Bl,
                                               const float* __restrict__ bias,
                                               const unsigned short* __restrict__ Rh,
                                               const unsigned short* __restrict__ Rl,
                                               const float* __restrict__ Rf,
                                               unsigned short* __restrict__ Ohi,
                                               unsigned short* __restrict__ Olo,
                                               float* __restrict__ Of,
                                               int M, int N, int K) {
  __shared__ unsigned short Ahs[128 * 40], Als[128 * 40];
  __shared__ unsigned short Bhs[64 * 40],  Bls[64 * 40];
  const int tid = threadIdx.x;
  const int m0 = blockIdx.y * 128, n0 = blockIdx.x * 64;
  const int lane = tid & 63, w = tid >> 6;
  const int wr = w >> 1, wc = w & 1;

  const int rA0 = tid >> 2, rA1 = 64 + (tid >> 2), chA = (tid & 3) * 8;
  const int rB = tid >> 2,  chB = (tid & 3) * 8;
  const size_t gA0 = (size_t)(m0 + rA0) * K + chA;
  const size_t gA1 = (size_t)(m0 + rA1) * K + chA;
  const size_t gB  = (size_t)(n0 + rB) * K + chB;
  const int lA0 = rA0 * 40 + chA, lA1 = rA1 * 40 + chA, lB = rB * 40 + chB;

  f32x4 acc[4][2];
  #pragma unroll
  for (int i = 0; i < 4; ++i)
    #pragma unroll
    for (int j = 0; j < 2; ++j) acc[i][j] = f32x4{0.f, 0.f, 0.f, 0.f};

  const int fr = lane & 15, fk = (lane >> 4) * 8;
  const int arow0 = (wr * 64 + fr) * 40 + fk;
  const int brow0 = (wc * 32 + fr) * 40 + fk;

  for (int k0 = 0; k0 < K; k0 += 32) {
    short8 a0h = *reinterpret_cast<const short8*>(&Ah[gA0 + k0]);
    short8 a1h = *reinterpret_cast<const short8*>(&Ah[gA1 + k0]);
    short8 a0l = *reinterpret_cast<const short8*>(&Al[gA0 + k0]);
    short8 a1l = *reinterpret_cast<const short8*>(&Al[gA1 + k0]);
    short8 bh  = *reinterpret_cast<const short8*>(&Bh[gB + k0]);
    short8 bl  = *reinterpret_cast<const short8*>(&Bl[gB + k0]);
    __syncthreads();
    *reinterpret_cast<short8*>(&Ahs[lA0]) = a0h;
    *reinterpret_cast<short8*>(&Ahs[lA1]) = a1h;
    *reinterpret_cast<short8*>(&Als[lA0]) = a0l;
    *reinterpret_cast<short8*>(&Als[lA1]) = a1l;
    *reinterpret_cast<short8*>(&Bhs[lB])  = bh;
    *reinterpret_cast<short8*>(&Bls[lB])  = bl;
    __syncthreads();

    short8 amh[4], aml[4], bnh[2], bnl[2];
    #pragma unroll
    for (int mf = 0; mf < 4; ++mf) {
      amh[mf] = *reinterpret_cast<const short8*>(&Ahs[arow0 + mf * 16 * 40]);
      aml[mf] = *reinterpret_cast<const short8*>(&Als[arow0 + mf * 16 * 40]);
    }
    #pragma unroll
    for (int nf = 0; nf < 2; ++nf) {
      bnh[nf] = *reinterpret_cast<const short8*>(&Bhs[brow0 + nf * 16 * 40]);
      bnl[nf] = *reinterpret_cast<const short8*>(&Bls[brow0 + nf * 16 * 40]);
    }
    #pragma unroll
    for (int mf = 0; mf < 4; ++mf)
      #pragma unroll
      for (int nf = 0; nf < 2; ++nf) {
        acc[mf][nf] = __builtin_amdgcn_mfma_f32_16x16x32_bf16(amh[mf], bnh[nf], acc[mf][nf], 0, 0, 0);
        acc[mf][nf] = __builtin_amdgcn_mfma_f32_16x16x32_bf16(amh[mf], bnl[nf], acc[mf][nf], 0, 0, 0);
        acc[mf][nf] = __builtin_amdgcn_mfma_f32_16x16x32_bf16(aml[mf], bnh[nf], acc[mf][nf], 0, 0, 0);
      }
  }

  const int er = (lane >> 4) * 4, ec = lane & 15;
  #pragma unroll
  for (int mf = 0; mf < 4; ++mf)
    #pragma unroll
    for (int nf = 0; nf < 2; ++nf)
      #pragma unroll
      for (int j = 0; j < 4; ++j) {
        const int m = m0 + wr * 64 + mf * 16 + er + j;
        const int n = n0 + wc * 32 + nf * 16 + ec;
        float v = acc[mf][nf][j];
        if constexpr (EPI == GO_PAIR_BIAS || EPI == GO_F32_BIAS_RESPAIR ||
                      EPI == GO_F32_BIAS_RESF32) v += bias[n];
        const size_t idx = (size_t)m * N + n;
        if constexpr (EPI == GO_PAIR_BIAS || EPI == GO_PAIR_NB) {
          unsigned short h = bf16r(v);
          Ohi[idx] = h; Olo[idx] = bf16r(v - bf2f(h));
        } else if constexpr (EPI == GO_F32) {
          Of[idx] = v;
        } else if constexpr (EPI == GO_F32_BIAS_RESPAIR) {
          Of[idx] = v + bf2f(Rh[idx]) + bf2f(Rl[idx]);
        } else {  // GO_F32_BIAS_RESF32 / GO_F32_RES_NB (Rf may alias Of)
          Of[idx] = v + Rf[idx];
        }
      }
}

// ---------------------------------------------------------------------------
// Dual GEMM (gate & up share A) — unchanged
// ---------------------------------------------------------------------------
__global__ __launch_bounds__(256) void gemm_gateup(const unsigned short* __restrict__ Ah,
                                                   const unsigned short* __restrict__ Al,
                                                   const unsigned short* __restrict__ Gh,
                                                   const unsigned short* __restrict__ Gl,
                                                   const unsigned short* __restrict__ Uh,
                                                   const unsigned short* __restrict__ Ul,
                                                   const float* __restrict__ bg,
                                                   const float* __restrict__ bu,
                                                   unsigned short* __restrict__ Ohi,
                                                   unsigned short* __restrict__ Olo,
                                                   int M, int N, int K) {
  __shared__ unsigned short Ahs[128 * 40], Als[128 * 40];
  __shared__ unsigned short Ghs[64 * 40], Gls[64 * 40], Uhs[64 * 40], Uls[64 * 40];
  const int tid = threadIdx.x;
  const int m0 = blockIdx.y * 128, n0 = blockIdx.x * 64;
  const int lane = tid & 63, w = tid >> 6;
  const int wr = w >> 1, wc = w & 1;

  const int rA0 = tid >> 2, rA1 = 64 + (tid >> 2), chA = (tid & 3) * 8;
  const int rB = tid >> 2, chB = (tid & 3) * 8;
  const size_t gA0 = (size_t)(m0 + rA0) * K + chA;
  const size_t gA1 = (size_t)(m0 + rA1) * K + chA;
  const size_t gB  = (size_t)(n0 + rB) * K + chB;
  const int lA0 = rA0 * 40 + chA, lA1 = rA1 * 40 + chA, lB = rB * 40 + chB;

  f32x4 accg[4][2], accu[4][2];
  #pragma unroll
  for (int i = 0; i < 4; ++i)
    #pragma unroll
    for (int j = 0; j < 2; ++j) {
      accg[i][j] = f32x4{0.f, 0.f, 0.f, 0.f};
      accu[i][j] = f32x4{0.f, 0.f, 0.f, 0.f};
    }

  const int fr = lane & 15, fk = (lane >> 4) * 8;
  const int arow0 = (wr * 64 + fr) * 40 + fk;
  const int brow0 = (wc * 32 + fr) * 40 + fk;

  for (int k0 = 0; k0 < K; k0 += 32) {
    short8 a0h = *reinterpret_cast<const short8*>(&Ah[gA0 + k0]);
    short8 a1h = *reinterpret_cast<const short8*>(&Ah[gA1 + k0]);
    short8 a0l = *reinterpret_cast<const short8*>(&Al[gA0 + k0]);
    short8 a1l = *reinterpret_cast<const short8*>(&Al[gA1 + k0]);
    short8 gh = *reinterpret_cast<const short8*>(&Gh[gB + k0]);
    short8 gl = *reinterpret_cast<const short8*>(&Gl[gB + k0]);
    short8 uh = *reinterpret_cast<const short8*>(&Uh[gB + k0]);
    short8 ul = *reinterpret_cast<const short8*>(&Ul[gB + k0]);
    __syncthreads();
    *reinterpret_cast<short8*>(&Ahs[lA0]) = a0h;
    *reinterpret_cast<short8*>(&Ahs[lA1]) = a1h;
    *reinterpret_cast<short8*>(&Als[lA0]) = a0l;
    *reinterpret_cast<short8*>(&Als[lA1]) = a1l;
    *reinterpret_cast<short8*>(&Ghs[lB]) = gh;
    *reinterpret_cast<short8*>(&Gls[lB]) = gl;
    *reinterpret_cast<short8*>(&Uhs[lB]) = uh;
    *reinterpret_cast<short8*>(&Uls[lB]) = ul;
    __syncthreads();

    short8 amh[4], aml[4];
    #pragma unroll
    for (int mf = 0; mf < 4; ++mf) {
      amh[mf] = *reinterpret_cast<const short8*>(&Ahs[arow0 + mf * 16 * 40]);
      aml[mf] = *reinterpret_cast<const short8*>(&Als[arow0 + mf * 16 * 40]);
    }
    #pragma unroll
    for (int nf = 0; nf < 2; ++nf) {
      short8 gnh = *reinterpret_cast<const short8*>(&Ghs[brow0 + nf * 16 * 40]);
      short8 gnl = *reinterpret_cast<const short8*>(&Gls[brow0 + nf * 16 * 40]);
      short8 unh = *reinterpret_cast<const short8*>(&Uhs[brow0 + nf * 16 * 40]);
      short8 unl = *reinterpret_cast<const short8*>(&Uls[brow0 + nf * 16 * 40]);
      #pragma unroll
      for (int mf = 0; mf < 4; ++mf) {
        accg[mf][nf] = __builtin_amdgcn_mfma_f32_16x16x32_bf16(amh[mf], gnh, accg[mf][nf], 0, 0, 0);
        accg[mf][nf] = __builtin_amdgcn_mfma_f32_16x16x32_bf16(amh[mf], gnl, accg[mf][nf], 0, 0, 0);
        accg[mf][nf] = __builtin_amdgcn_mfma_f32_16x16x32_bf16(aml[mf], gnh, accg[mf][nf], 0, 0, 0);
        accu[mf][nf] = __builtin_amdgcn_mfma_f32_16x16x32_bf16(amh[mf], unh, accu[mf][nf], 0, 0, 0);
        accu[mf][nf] = __builtin_amdgcn_mfma_f32_16x16x32_bf16(amh[mf], unl, accu[mf][nf], 0, 0, 0);
        accu[mf][nf] = __builtin_amdgcn_mfma_f32_16x16x32_bf16(aml[mf], unh, accu[mf][nf], 0, 0, 0);
      }
    }
  }

  const int er = (lane >> 4) * 4, ec = lane & 15;
  #pragma unroll
  for (int mf = 0; mf < 4; ++mf)
    #pragma unroll
    for (int nf = 0; nf < 2; ++nf)
      #pragma unroll
      for (int j = 0; j < 4; ++j) {
        const int m = m0 + wr * 64 + mf * 16 + er + j;
        const int n = n0 + wc * 32 + nf * 16 + ec;
        float g = accg[mf][nf][j] + bg[n];
        float u = accu[mf][nf][j] + bu[n];
        float f = (g / (1.f + expf(-g))) * u;
        const size_t idx = (size_t)m * N + n;
        unsigned short h = bf16r(f);
        Ohi[idx] = h; Olo[idx] = bf16r(f - bf2f(h));
      }
}

// ---------------------------------------------------------------------------
// Sparse attention v5: QBLK=16, 4 waves, chunk-cooperative, FULLY UNROLLED
// chunk loop so key[4][32] is always statically indexed (VGPR-resident).
// ---------------------------------------------------------------------------
__global__ __launch_bounds__(256, 2) void attn_kernel(
    const unsigned short* __restrict__ qh, const unsigned short* __restrict__ ql,
    const unsigned short* __restrict__ kh, const unsigned short* __restrict__ kl,
    const float* __restrict__ vm,
    unsigned short* __restrict__ aoh, unsigned short* __restrict__ aol,
    const int* __restrict__ topk_p) {
  constexpr int QB = 16;
  constexpr int NJ = N_ / 64;               // 32 keys/lane/row
  __shared__ float Sb[QB][513];             // 32.8 KB chunk strip
  __shared__ int   selIdx[4][128];
  __shared__ float selS[4][128];

  const int tid = threadIdx.x;
  const int lane = tid & 63, w = tid >> 6;
  // XCD-chunked bijective swizzle: 4096 = 8 XCDs x 512
  const int bid = ((blockIdx.x & 7) << 9) | (blockIdx.x >> 3);
  const int qt = bid & 127;
  const int hh = (bid >> 7) & (H_ - 1);
  const int bb = bid >> 11;
  const int q0 = qt * QB;

  const int fr = lane & 15;                 // frag row (A) / col (B)
  const int fk = (lane >> 4) * 8;           // frag k-offset (bf16 units)

  // Q fragments (each wave holds the same A-frag for the 16 block rows)
  const size_t qbase = ((size_t)(bb * N_ + q0 + fr)) * D_ + hh * HD_ + fk;
  short8 ah0 = *reinterpret_cast<const short8*>(qh + qbase);
  short8 ah1 = *reinterpret_cast<const short8*>(qh + qbase + 32);
  short8 al0 = *reinterpret_cast<const short8*>(ql + qbase);
  short8 al1 = *reinterpret_cast<const short8*>(ql + qbase + 32);

  unsigned key[4][NJ];                      // wave w owns rows {w,w+4,w+8,w+12}
  const int r0 = (lane >> 4) * 4;

  // ---- phase 1: 4 chunks of 512 cols, cooperative. UNROLLED (rule #20:
  // runtime cc would force key[] into scratch; R7/R8 lost ~2x to this). ----
  #pragma unroll
  for (int cc = 0; cc < 4; ++cc) {
    const int colbase = cc * 512 + w * 128;
    const size_t kwb = ((size_t)(bb * N_ + colbase + fr)) * D_ + hh * HD_ + fk;

    f32x4 acc[8];
    #pragma unroll
    for (int ctl = 0; ctl < 8; ++ctl) acc[ctl] = f32x4{0.f, 0.f, 0.f, 0.f};
    #pragma unroll
    for (int ctl = 0; ctl < 8; ++ctl) {
      const size_t kb0 = kwb + (size_t)ctl * 16 * D_;
      short8 bh0 = *reinterpret_cast<const short8*>(kh + kb0);
      short8 bh1 = *reinterpret_cast<const short8*>(kh + kb0 + 32);
      short8 bl0 = *reinterpret_cast<const short8*>(kl + kb0);
      short8 bl1 = *reinterpret_cast<const short8*>(kl + kb0 + 32);
      acc[ctl] = __builtin_amdgcn_mfma_f32_16x16x32_bf16(ah0, bh0, acc[ctl], 0, 0, 0);
      acc[ctl] = __builtin_amdgcn_mfma_f32_16x16x32_bf16(ah0, bl0, acc[ctl], 0, 0, 0);
      acc[ctl] = __builtin_amdgcn_mfma_f32_16x16x32_bf16(al0, bh0, acc[ctl], 0, 0, 0);
      acc[ctl] = __builtin_amdgcn_mfma_f32_16x16x32_bf16(ah1, bh1, acc[ctl], 0, 0, 0);
      acc[ctl] = __builtin_amdgcn_mfma_f32_16x16x32_bf16(ah1, bl1, acc[ctl], 0, 0, 0);
      acc[ctl] = __builtin_amdgcn_mfma_f32_16x16x32_bf16(al1, bh1, acc[ctl], 0, 0, 0);
    }

    __syncthreads();                        // prev chunk's Sb reads complete
    #pragma unroll
    for (int ctl = 0; ctl < 8; ++ctl) {
      const int col = w * 128 + ctl * 16 + fr;         // within-chunk col
      #pragma unroll
      for (int j = 0; j < 4; ++j)
        Sb[r0 + j][col] = acc[ctl][j] * 0.125f;        // exact pow-2 scale
    }
    __syncthreads();

    #pragma unroll
    for (int rr = 0; rr < 4; ++rr) {
      const int row = w + rr * 4;
      #pragma unroll
      for (int jj = 0; jj < 8; ++jj)
        key[rr][cc * 8 + jj] = fkey(Sb[row][jj * 64 + lane]);
    }
  }

  int topk = *topk_p;
  if (topk > N_) topk = N_;
  const float* Vb = vm + (size_t)bb * N_ * D_ + hh * HD_;

  // ---- phases 2+3 per owned row ----
  #pragma unroll
  for (int rr = 0; rr < 4; ++rr) {
    // row max
    unsigned kmax = 0;
    #pragma unroll
    for (int j = 0; j < NJ; ++j) kmax = (key[rr][j] > kmax) ? key[rr][j] : kmax;
    #pragma unroll
    for (int o = 32; o; o >>= 1) {
      unsigned t = __shfl_xor(kmax, o);
      kmax = (t > kmax) ? t : kmax;
    }
    const float smax = fval(kmax);

    // exact kth-largest threshold (radix on keys, early exit at c==topk)
    unsigned thr = 0u;
    if (topk < N_) {
      for (int bit = 31; bit >= 0; --bit) {
        const unsigned cand = thr | (1u << bit);
        int c = 0;
        #pragma unroll
        for (int j = 0; j < NJ; ++j)
          c += __popcll(__ballot(key[rr][j] >= cand));
        if (c >= topk) {
          thr = cand;
          if (c == topk) break;   // selection set already exact
        }
      }
    }

    // compaction: store (idx, raw score)
    int base = 0;
    #pragma unroll
    for (int j = 0; j < NJ; ++j) {
      const bool sel = key[rr][j] >= thr;
      const unsigned long long m = __ballot(sel);
      if (sel) {
        const int pos = base + (int)__popcll(m & ((1ull << lane) - 1ull));
        if (pos < 128) {
          selIdx[w][pos] = j * 64 + lane;
          selS[w][pos]   = fval(key[rr][j]);
        }
      }
      base += (int)__popcll(m);
    }
    const int cnt = (base > 128) ? 128 : base;

    // deferred expf: 2 per lane max, then wave-reduce wsum
    float wsum = 0.f;
    if (lane < cnt) {
      float e = expf(selS[w][lane] - smax);
      selS[w][lane] = e; wsum += e;
    }
    if (lane + 64 < cnt) {
      float e = expf(selS[w][lane + 64] - smax);
      selS[w][lane + 64] = e; wsum += e;
    }
    #pragma unroll
    for (int o = 32; o; o >>= 1) wsum += __shfl_xor(wsum, o);

    // batched parallel V gather (lane = d)
    float outv = 0.f;
    int i = 0;
    for (; i + 16 <= cnt; i += 16) {
      int ix[16]; float wv[16], vv[16];
      #pragma unroll
      for (int t = 0; t < 16; ++t) {
        ix[t] = selIdx[w][i + t];
        wv[t] = selS[w][i + t];
      }
      #pragma unroll
      for (int t = 0; t < 16; ++t) vv[t] = Vb[(size_t)ix[t] * D_ + lane];
      #pragma unroll
      for (int t = 0; t < 16; ++t) outv += wv[t] * vv[t];
    }
    for (; i < cnt; ++i)
      outv += selS[w][i] * Vb[(size_t)selIdx[w][i] * D_ + lane];

    const float o = outv / wsum;
    const size_t oidx = ((size_t)bb * N_ + q0 + w + rr * 4) * D_ + hh * HD_ + lane;
    unsigned short hsh = bf16r(o);
    aoh[oidx] = hsh; aol[oidx] = bf16r(o - bf2f(hsh));
  }
}

// ---------------------------------------------------------------------------
// Orchestration. ws extent = 100 MB, lifetime aliasing unchanged.
// ---------------------------------------------------------------------------
extern "C" void kernel_launch(void* const* d_in, const int* in_sizes, int n_in,
                              void* d_out, int out_size, void* d_ws, size_t ws_size,
                              hipStream_t stream) {
  const float* x      = (const float*)d_in[0];
  const float* ln1_g  = (const float*)d_in[1];
  const float* ln1_b  = (const float*)d_in[2];
  const float* w_in   = (const float*)d_in[3];
  const float* b_in   = (const float*)d_in[4];
  const float* wq     = (const float*)d_in[5];
  const float* wk     = (const float*)d_in[6];
  const float* wv     = (const float*)d_in[7];
  const float* wo     = (const float*)d_in[8];
  const float* bo     = (const float*)d_in[9];
  const float* ln2_g  = (const float*)d_in[10];
  const float* ln2_b  = (const float*)d_in[11];
  const float* w_up   = (const float*)d_in[12];
  const float* b_up   = (const float*)d_in[13];
  const float* w_gate = (const float*)d_in[14];
  const float* b_gate = (const float*)d_in[15];
  const float* w_down = (const float*)d_in[16];
  const float* b_down = (const float*)d_in[17];
  const int*   topk   = (const int*)d_in[18];
  float* out = (float*)d_out;

  char* p = (char*)d_ws;
  const size_t MB = 1024 * 1024;
  unsigned short* Wi_h = (unsigned short*)(p + 0 * MB);
  unsigned short* Wi_l = (unsigned short*)(p + 2 * MB);
  unsigned short* Wq_h = (unsigned short*)(p + 4 * MB);
  unsigned short* Wq_l = (unsigned short*)(p + 6 * MB);
  unsigned short* Wk_h = (unsigned short*)(p + 8 * MB);
  unsigned short* Wk_l = (unsigned short*)(p + 10 * MB);
  unsigned short* Wv_h = (unsigned short*)(p + 12 * MB);
  unsigned short* Wv_l = (unsigned short*)(p + 14 * MB);
  unsigned short* Wo_h = (unsigned short*)(p + 16 * MB);
  unsigned short* Wo_l = (unsigned short*)(p + 18 * MB);
  unsigned short* Wd0_h = (unsigned short*)(p + 20 * MB);
  unsigned short* Wd0_l = (unsigned short*)(p + 24 * MB);
  unsigned short* Wd1_h = (unsigned short*)(p + 28 * MB);
  unsigned short* Wd1_l = (unsigned short*)(p + 32 * MB);
  unsigned short* hp_h = (unsigned short*)(p + 36 * MB);
  unsigned short* hp_l = (unsigned short*)(p + 44 * MB);
  unsigned short* ff_h = (unsigned short*)(p + 36 * MB);
  unsigned short* ff_l = (unsigned short*)(p + 44 * MB);
  unsigned short* xn_h = (unsigned short*)(p + 52 * MB);
  unsigned short* xn_l = (unsigned short*)(p + 60 * MB);
  unsigned short* q_h  = (unsigned short*)(p + 52 * MB);
  unsigned short* q_l  = (unsigned short*)(p + 60 * MB);
  unsigned short* k_h  = (unsigned short*)(p + 68 * MB);
  unsigned short* k_l  = (unsigned short*)(p + 76 * MB);
  float*          vb   = (float*)(p + 84 * MB);
  unsigned short* Wg_h = (unsigned short*)(p + 52 * MB);
  unsigned short* Wg_l = (unsigned short*)(p + 60 * MB);
  unsigned short* Wu_h = (unsigned short*)(p + 68 * MB);
  unsigned short* Wu_l = (unsigned short*)(p + 76 * MB);
  unsigned short* f1_h = (unsigned short*)(p + 84 * MB);
  unsigned short* ao_h = (unsigned short*)(p + 0 * MB);
  unsigned short* ao_l = (unsigned short*)(p + 8 * MB);
  unsigned short* f1_l = (unsigned short*)(p + 0 * MB);

  const dim3 blk(256);
  const dim3 gW1k(32, 32);
  const dim3 gWgu(128, 32);
  const dim3 gWd(32, 64);
  const dim3 g1024(16, 32);
  const dim3 g2048(32, 32);

  wconv_kernel<<<gW1k, blk, 0, stream>>>(w_in, Wi_h, Wi_l, 1024, 1024);
  wconv_kernel<<<gW1k, blk, 0, stream>>>(wq, Wq_h, Wq_l, 1024, 1024);
  wconv_kernel<<<gW1k, blk, 0, stream>>>(wk, Wk_h, Wk_l, 1024, 1024);
  wconv_kernel<<<gW1k, blk, 0, stream>>>(wv, Wv_h, Wv_l, 1024, 1024);
  wconv_kernel<<<gW1k, blk, 0, stream>>>(wo, Wo_h, Wo_l, 1024, 1024);
  wconv_kernel<<<gWd, blk, 0, stream>>>(w_down,               Wd0_h, Wd0_l, 2048, 1024);
  wconv_kernel<<<gWd, blk, 0, stream>>>(w_down + 2048 * 1024, Wd1_h, Wd1_l, 2048, 1024);

  ln_kernel<<<M_, blk, 0, stream>>>(x, ln1_g, ln1_b, xn_h, xn_l);
  gemm_sb<GO_PAIR_BIAS><<<g1024, blk, 0, stream>>>(xn_h, xn_l, Wi_h, Wi_l, b_in,
      nullptr, nullptr, nullptr, hp_h, hp_l, nullptr, M_, 1024, 1024);
  gemm_sb<GO_PAIR_NB><<<g1024, blk, 0, stream>>>(hp_h, hp_l, Wq_h, Wq_l, nullptr,
      nullptr, nullptr, nullptr, q_h, q_l, nullptr, M_, 1024, 1024);
  gemm_sb<GO_PAIR_NB><<<g1024, blk, 0, stream>>>(hp_h, hp_l, Wk_h, Wk_l, nullptr,
      nullptr, nullptr, nullptr, k_h, k_l, nullptr, M_, 1024, 1024);
  gemm_sb<GO_F32><<<g1024, blk, 0, stream>>>(hp_h, hp_l, Wv_h, Wv_l, nullptr,
      nullptr, nullptr, nullptr, nullptr, nullptr, vb, M_, 1024, 1024);

  attn_kernel<<<B_ * H_ * (N_ / 16), blk, 0, stream>>>(q_h, q_l, k_h, k_l, vb,
      ao_h, ao_l, topk);

  wconv_kernel<<<gWgu, blk, 0, stream>>>(w_gate, Wg_h, Wg_l, 1024, 4096);
  wconv_kernel<<<gWgu, blk, 0, stream>>>(w_up,   Wu_h, Wu_l, 1024, 4096);

  gemm_sb<GO_F32_BIAS_RESPAIR><<<g1024, blk, 0, stream>>>(ao_h, ao_l, Wo_h, Wo_l, bo,
      hp_h, hp_l, nullptr, nullptr, nullptr, out, M_, 1024, 1024);

  ln_kernel<<<M_, blk, 0, stream>>>(out, ln2_g, ln2_b, ff_h, ff_l);

  gemm_gateup<<<g2048, blk, 0, stream>>>(ff_h, ff_l,
      Wg_h, Wg_l, Wu_h, Wu_l, b_gate, b_up, f1_h, f1_l, M_, 2048, 1024);
  gemm_sb<GO_F32_BIAS_RESF32><<<g1024, blk, 0, stream>>>(f1_h, f1_l, Wd0_h, Wd0_l,
      b_down, nullptr, nullptr, out, nullptr, nullptr, out, M_, 1024, 2048);
  gemm_gateup<<<g2048, blk, 0, stream>>>(ff_h, ff_l,
      Wg_h + (size_t)2048 * 1024, Wg_l + (size_t)2048 * 1024,
      Wu_h + (size_t)2048 * 1024, Wu_l + (size_t)2048 * 1024,
      b_gate + 2048, b_up + 2048, f1_h, f1_l, M_, 2048, 1024);
  gemm_sb<GO_F32_RES_NB><<<g1024, blk, 0, stream>>>(f1_h, f1_l, Wd1_h, Wd1_l,
      nullptr, nullptr, nullptr, out, nullptr, nullptr, out, M_, 1024, 2048);
}